// Round 9
// baseline (248.707 us; speedup 1.0000x reference)
//
#include <hip/hip_runtime.h>
#include <hip/hip_bf16.h>

// ---------------- problem constants ----------------
#define NTOK   8192
#define TOPK   2
#define NROWS  (NTOK*TOPK)      // 16384
#define NEXP   8
#define KDIM   1024             // inner (INTER)
#define NDIM   2048             // output (HIDDEN)
#define TM     128              // tile rows
#define TN     256              // tile cols
#define BK     64
#define MAXYT  136              // sum ceil(cnt_e/128) <= 128+8
#define NXT    (NDIM/TN)        // 8
#define GRID_G (MAXYT*NXT)      // 1088 = 8*136

typedef __bf16 bf16_t;
typedef __bf16 bf16x8 __attribute__((ext_vector_type(8)));
typedef float  f32x4  __attribute__((ext_vector_type(4)));

static_assert(sizeof(bf16x8) == 16, "bf16x8 must be 16B");

// ---------------- ws layout (bytes) ----------------
#define OFF_TW    ((size_t)0)                    // 16384 f32
#define OFF_EP    ((size_t)(1<<16))              // 16384 u32 (e<<24|pos)
#define OFF_CNT   ((size_t)(1<<17))              // 8 i32
#define OFF_RL    ((size_t)(1<<18))              // 8*16384 i32
#define OFF_WB    ((size_t)(1<<20))              // 8*2048*1024 bf16 = 32MB
#define OFF_SCR   ((size_t)(34u<<20))            // 16384*2048 bf16 = 64MB (slot order)

__device__ __forceinline__ void gload_lds16(const bf16_t* g, const char* l) {
  __builtin_amdgcn_global_load_lds(
      (const __attribute__((address_space(1))) void*)g,
      (__attribute__((address_space(3))) void*)(void*)l, 16, 0, 0);
}

#define CVT8(lo,hi) bf16x8{ (bf16_t)(lo).x,(bf16_t)(lo).y,(bf16_t)(lo).z,(bf16_t)(lo).w, \
                            (bf16_t)(hi).x,(bf16_t)(hi).y,(bf16_t)(hi).z,(bf16_t)(hi).w }

// ---------------- 1. routing: softmax + top2 + bucket + (e,pos) ----------------
__global__ void routing_kernel(const float* __restrict__ logits,
                               float* __restrict__ tw,
                               int* __restrict__ cnt, int* __restrict__ rowlist,
                               unsigned* __restrict__ ep) {
  int t = blockIdx.x * blockDim.x + threadIdx.x;
  if (t >= NTOK) return;
  float4 a = *(const float4*)(logits + (size_t)t*NEXP);
  float4 b = *(const float4*)(logits + (size_t)t*NEXP + 4);
  float l[8] = {a.x, a.y, a.z, a.w, b.x, b.y, b.z, b.w};
  float m = l[0];
#pragma unroll
  for (int i = 1; i < 8; i++) m = fmaxf(m, l[i]);
  float p[8], s = 0.f;
#pragma unroll
  for (int i = 0; i < 8; i++) { p[i] = __expf(l[i] - m); s += p[i]; }
  int e0 = 0; float b0 = p[0];
#pragma unroll
  for (int i = 1; i < 8; i++) if (p[i] > b0) { b0 = p[i]; e0 = i; }
  int e1 = (e0 == 0) ? 1 : 0; float b1 = p[e1];
#pragma unroll
  for (int i = 0; i < 8; i++) if (i != e0 && p[i] > b1) { b1 = p[i]; e1 = i; }
  float inv = 1.f / s;
  tw[2*t]   = b0 * inv;
  tw[2*t+1] = b1 * inv;
  int pos0 = atomicAdd(&cnt[e0], 1);
  rowlist[(size_t)e0*NROWS + pos0] = 2*t;
  ep[2*t] = ((unsigned)e0 << 24) | (unsigned)pos0;
  int pos1 = atomicAdd(&cnt[e1], 1);
  rowlist[(size_t)e1*NROWS + pos1] = 2*t + 1;
  ep[2*t+1] = ((unsigned)e1 << 24) | (unsigned)pos1;
}

// ---------------- 2. convert+transpose w -> bf16 [E][N][K] ----------------
__global__ void cvt_w_kernel(const float* __restrict__ w, bf16_t* __restrict__ wb) {
  __shared__ float tf[64*65];
  int e  = blockIdx.z;
  int n0 = blockIdx.x * 64;
  int k0 = blockIdx.y * 64;
  int t  = threadIdx.x;
  const float* src = w + (size_t)e*KDIM*NDIM + (size_t)k0*NDIM + n0;
#pragma unroll
  for (int i = 0; i < 4; i++) {
    int idx = t + i*256;
    int kr  = idx >> 4;
    int nc4 = (idx & 15) * 4;
    float4 v = *(const float4*)(src + (size_t)kr*NDIM + nc4);
    tf[kr*65 + nc4+0] = v.x; tf[kr*65 + nc4+1] = v.y;
    tf[kr*65 + nc4+2] = v.z; tf[kr*65 + nc4+3] = v.w;
  }
  __syncthreads();
  bf16_t* dst = wb + (size_t)e*NDIM*KDIM + (size_t)n0*KDIM + k0;
#pragma unroll
  for (int i = 0; i < 2; i++) {
    int idx = t + i*256;
    int nr  = idx >> 3;
    int kc  = (idx & 7) * 8;
    bf16x8 o;
#pragma unroll
    for (int j = 0; j < 8; j++) o[j] = (bf16_t)tf[(kc+j)*65 + nr];
    *(bf16x8*)(dst + (size_t)nr*KDIM + kc) = o;
  }
}

// ---------------- 3. grouped GEMM: 128x256, BK=64, A reg-staged from fp32 ----
// 8 waves (2M x 4N). A: gather rows via rowlist from fp32 x, cvt in reg,
// ds_write swizzled (phys slot = logical ^ (row&7), 2-way max per phase).
// B: DMA from wb, linear dest (r8-proven). A-prefetch issues after barrier #2
// -> in flight across the MFMA phase. Epilogue sequential to scr (slot order).
__global__ __launch_bounds__(512)
void gemm_kernel(const float*  __restrict__ x,      // [NROWS][KDIM] fp32
                 const bf16_t* __restrict__ wb,     // [NEXP][NDIM][KDIM]
                 const int*    __restrict__ cnt,
                 const int*    __restrict__ rowlist,
                 bf16_t*       __restrict__ scrb) { // [NROWS][NDIM] slot order
  __shared__ char smem[49152];   // A[128][64]bf16 @0 (16KB), B[256][64] @16384 (32KB)

  // XCD-bijective swizzle: 1088 = 8*136, n-tile fastest
  int bid = blockIdx.x;
  int lin = (bid & 7) * (GRID_G/8) + (bid >> 3);
  int xt  = lin & (NXT-1);
  int yt  = lin >> 3;

  // inline worklist: expert, slot base of tile (rowbase), expert slot base (rb)
  int e = -1, rowbase = 0, expbase = 0, nrows = 0;
  {
    int a0 = 0, rb = 0;
#pragma unroll
    for (int ee = 0; ee < NEXP; ee++) {
      int c  = cnt[ee];
      int nt = (c + TM - 1) >> 7;
      if (yt >= a0 && yt < a0 + nt) {
        e = ee; rowbase = rb + (yt - a0)*TM; expbase = rb;
        nrows = c - (yt - a0)*TM; if (nrows > TM) nrows = TM;
      }
      a0 += nt; rb += c;
    }
  }
  if (e < 0) return;
  const int n0 = xt * TN;

  const int t    = threadIdx.x;
  const int lane = t & 63;
  const int wv   = t >> 6;         // 0..7
  const int wm   = wv >> 2;        // 0..1
  const int wn   = wv & 3;         // 0..3
  const int lr   = lane & 15;
  const int l4   = lane >> 4;

  const int* rl = rowlist + (size_t)e*NROWS + (rowbase - expbase);

  // ---- A staging: lane -> rows (wv*8 + lane>>3) and +64; logical slot lane&7
  const int slog  = lane & 7;
  const int arow0 = wv*8 + (lane >> 3);      // 0..63
  const int arow1 = arow0 + 64;              // 64..127
  const int wA0 = arow0*128 + ((slog ^ (arow0 & 7)) << 4);
  const int wA1 = arow1*128 + ((slog ^ (arow1 & 7)) << 4);
  int i0 = arow0 < nrows ? arow0 : nrows-1;
  int i1 = arow1 < nrows ? arow1 : nrows-1;
  const float* srcA0 = x + (size_t)rl[i0]*KDIM + slog*8;
  const float* srcA1 = x + (size_t)rl[i1]*KDIM + slog*8;

  // ---- B staging (DMA): thread t -> row t>>3 (+64i), phys slot t&7 ----
  const int koff = ((t & 7) ^ ((t >> 3) & 7)) * 8;
  const bf16_t* gBb = wb + ((size_t)e*NDIM + n0 + (t >> 3))*KDIM + koff;
  const char* dB = &smem[16384 + t*16];

  // ---- fragment read offsets (byte, swizzled) ----
  const int aoff0 = (wm*64 + lr)*128 + ((l4 ^ (lr & 7)) << 4);
  const int boff0 = 16384 + (wn*64 + lr)*128 + ((l4 ^ (lr & 7)) << 4);

  f32x4 acc[4][4] = {};

  // prologue: A regs for step 0
  float4 a00 = *(const float4*)srcA0, a01 = *(const float4*)(srcA0+4);
  float4 a10 = *(const float4*)srcA1, a11 = *(const float4*)(srcA1+4);
  srcA0 += BK; srcA1 += BK;

#pragma unroll 1
  for (int kt = 0; kt < KDIM/BK; ++kt) {
    __syncthreads();                 // previous frag reads done; LDS free
    *(bf16x8*)&smem[wA0] = CVT8(a00, a01);
    *(bf16x8*)&smem[wA1] = CVT8(a10, a11);
    gload_lds16(gBb,            dB);
    gload_lds16(gBb + 64*KDIM,  dB + 8192);
    gload_lds16(gBb + 128*KDIM, dB + 16384);
    gload_lds16(gBb + 192*KDIM, dB + 24576);
    gBb += BK;
    __syncthreads();                 // B landed, A visible
    if (kt < KDIM/BK - 1) {          // prefetch A(kt+1): flies across MFMAs
      a00 = *(const float4*)srcA0; a01 = *(const float4*)(srcA0+4);
      a10 = *(const float4*)srcA1; a11 = *(const float4*)(srcA1+4);
      srcA0 += BK; srcA1 += BK;
    }

    bf16x8 af[4][2], bf[4][2];
#pragma unroll
    for (int mi = 0; mi < 4; mi++) {
      af[mi][0] = *(const bf16x8*)&smem[aoff0 + mi*2048];
      af[mi][1] = *(const bf16x8*)&smem[(aoff0 + mi*2048) ^ 64];
    }
#pragma unroll
    for (int ni = 0; ni < 4; ni++) {
      bf[ni][0] = *(const bf16x8*)&smem[boff0 + ni*2048];
      bf[ni][1] = *(const bf16x8*)&smem[(boff0 + ni*2048) ^ 64];
    }
#pragma unroll
    for (int mi = 0; mi < 4; mi++)
#pragma unroll
      for (int ni = 0; ni < 4; ni++) {
        acc[mi][ni] = __builtin_amdgcn_mfma_f32_16x16x32_bf16(af[mi][0], bf[ni][0], acc[mi][ni], 0, 0, 0);
        acc[mi][ni] = __builtin_amdgcn_mfma_f32_16x16x32_bf16(af[mi][1], bf[ni][1], acc[mi][ni], 0, 0, 0);
      }
  }

  // ---- epilogue: sequential slot rows, no scale ----
#pragma unroll
  for (int mi = 0; mi < 4; mi++) {
#pragma unroll
    for (int jj = 0; jj < 4; jj++) {
      int rbw = wm*64 + mi*16 + l4*4 + jj;
      if (rbw < nrows) {
        bf16_t* dst = scrb + (size_t)(rowbase + rbw)*NDIM + n0 + wn*64 + lr;
#pragma unroll
        for (int ni = 0; ni < 4; ni++) dst[ni*16] = (bf16_t)acc[mi][ni][jj];
      }
    }
  }
}

// ---------------- 4. reduce: out[t] = tw0*scr[slot(2t)] + tw1*scr[slot(2t+1)] -
__global__ void reduce_kernel(const bf16_t* __restrict__ scr,
                              const unsigned* __restrict__ ep,
                              const float* __restrict__ tw,
                              const int* __restrict__ cnt,
                              float* __restrict__ out) {
  int tk = blockIdx.x;                 // token
  int c  = threadIdx.x;                // 256 threads, 8 cols each
  int base[NEXP]; int acc = 0;
#pragma unroll
  for (int ee = 0; ee < NEXP; ee++) { base[ee] = acc; acc += cnt[ee]; }
  unsigned p0 = ep[2*tk], p1 = ep[2*tk+1];
  int s0 = base[p0 >> 24] + (int)(p0 & 0xFFFFFFu);
  int s1 = base[p1 >> 24] + (int)(p1 & 0xFFFFFFu);
  float w0 = tw[2*tk], w1 = tw[2*tk+1];
  bf16x8 a = *(const bf16x8*)(scr + (size_t)s0*NDIM + c*8);
  bf16x8 b = *(const bf16x8*)(scr + (size_t)s1*NDIM + c*8);
  float4 o0 = { w0*(float)a[0]+w1*(float)b[0], w0*(float)a[1]+w1*(float)b[1],
                w0*(float)a[2]+w1*(float)b[2], w0*(float)a[3]+w1*(float)b[3] };
  float4 o1 = { w0*(float)a[4]+w1*(float)b[4], w0*(float)a[5]+w1*(float)b[5],
                w0*(float)a[6]+w1*(float)b[6], w0*(float)a[7]+w1*(float)b[7] };
  float* dst = out + (size_t)tk*NDIM + c*8;
  *(float4*)(dst)     = o0;
  *(float4*)(dst + 4) = o1;
}

// ---------------- launch ----------------
extern "C" void kernel_launch(void* const* d_in, const int* in_sizes, int n_in,
                              void* d_out, int out_size, void* d_ws, size_t ws_size,
                              hipStream_t stream) {
  const float* x      = (const float*)d_in[0];
  const float* w      = (const float*)d_in[1];
  const float* logits = (const float*)d_in[2];
  float* out = (float*)d_out;

  char* ws = (char*)d_ws;
  float*    tw      = (float*)   (ws + OFF_TW);
  unsigned* ep      = (unsigned*)(ws + OFF_EP);
  int*      cnt     = (int*)     (ws + OFF_CNT);
  int*      rowlist = (int*)     (ws + OFF_RL);
  bf16_t*   wb      = (bf16_t*)  (ws + OFF_WB);
  bf16_t*   scrb    = (bf16_t*)  (ws + OFF_SCR);

  hipMemsetAsync(cnt, 0, NEXP * sizeof(int), stream);
  routing_kernel<<<NTOK/256, 256, 0, stream>>>(logits, tw, cnt, rowlist, ep);
  cvt_w_kernel<<<dim3(NDIM/64, KDIM/64, NEXP), 256, 0, stream>>>(w, wb);
  gemm_kernel<<<GRID_G, 512, 0, stream>>>(x, wb, cnt, rowlist, scrb);
  reduce_kernel<<<NTOK, 256, 0, stream>>>(scrb, ep, tw, cnt, out);
}

// Round 10
// 225.523 us; speedup vs baseline: 1.1028x; 1.1028x over previous
//
#include <hip/hip_runtime.h>
#include <hip/hip_bf16.h>

// ---------------- problem constants ----------------
#define NTOK   8192
#define TOPK   2
#define NROWS  (NTOK*TOPK)      // 16384
#define NEXP   8
#define KDIM   1024             // inner (INTER)
#define NDIM   2048             // output (HIDDEN)
#define TM     128              // tile rows
#define TN     256              // tile cols
#define BK     64
#define MAXYT  136              // sum ceil(cnt_e/128) <= 128+8
#define NXT    (NDIM/TN)        // 8
#define GRID_G (MAXYT*NXT)      // 1088 = 8*136

typedef __bf16 bf16_t;
typedef __bf16 bf16x8 __attribute__((ext_vector_type(8)));
typedef float  f32x4  __attribute__((ext_vector_type(4)));

static_assert(sizeof(bf16x8) == 16, "bf16x8 must be 16B");

// ---------------- ws layout (bytes) ----------------
#define OFF_TW    ((size_t)0)                    // 16384 f32
#define OFF_INV   ((size_t)(1<<16))              // 16384 i32
#define OFF_CNT   ((size_t)(1<<17))              // 8 i32
#define OFF_RL    ((size_t)(1<<18))              // 8*16384 i32
#define OFF_XP    ((size_t)(1<<20))              // 16384*1024 bf16 = 32MB (permuted)
#define OFF_WB    ((size_t)(34u<<20))            // 8*2048*1024 bf16 = 32MB
#define OFF_SCR   ((size_t)(68u<<20))            // 16384*2048 bf16 = 64MB (permuted order)

__device__ __forceinline__ void gload_lds16(const bf16_t* g, const char* l) {
  __builtin_amdgcn_global_load_lds(
      (const __attribute__((address_space(1))) void*)g,
      (__attribute__((address_space(3))) void*)(void*)l, 16, 0, 0);
}

// ---------------- 1. routing: softmax + top2 + bucket ----------------
__global__ void routing_kernel(const float* __restrict__ logits,
                               float* __restrict__ tw,
                               int* __restrict__ cnt, int* __restrict__ rowlist) {
  int t = blockIdx.x * blockDim.x + threadIdx.x;
  if (t >= NTOK) return;
  float4 a = *(const float4*)(logits + (size_t)t*NEXP);
  float4 b = *(const float4*)(logits + (size_t)t*NEXP + 4);
  float l[8] = {a.x, a.y, a.z, a.w, b.x, b.y, b.z, b.w};
  float m = l[0];
#pragma unroll
  for (int i = 1; i < 8; i++) m = fmaxf(m, l[i]);
  float p[8], s = 0.f;
#pragma unroll
  for (int i = 0; i < 8; i++) { p[i] = __expf(l[i] - m); s += p[i]; }
  int e0 = 0; float b0 = p[0];
#pragma unroll
  for (int i = 1; i < 8; i++) if (p[i] > b0) { b0 = p[i]; e0 = i; }
  int e1 = (e0 == 0) ? 1 : 0; float b1 = p[e1];
#pragma unroll
  for (int i = 0; i < 8; i++) if (i != e0 && p[i] > b1) { b1 = p[i]; e1 = i; }
  float inv = 1.f / s;
  tw[2*t]   = b0 * inv;
  tw[2*t+1] = b1 * inv;
  int pos0 = atomicAdd(&cnt[e0], 1);
  rowlist[(size_t)e0*NROWS + pos0] = 2*t;
  int pos1 = atomicAdd(&cnt[e1], 1);
  rowlist[(size_t)e1*NROWS + pos1] = 2*t + 1;
}

// ---------------- 2. cvt_x_perm: x -> bf16, expert-sorted order; emit inv ----
__global__ void cvt_x_perm_kernel(const float* __restrict__ x,
                                  const int* __restrict__ cnt,
                                  const int* __restrict__ rowlist,
                                  bf16_t* __restrict__ xp,
                                  int* __restrict__ inv) {
  int s = blockIdx.x * 2 + (threadIdx.x >> 7);     // 2 rows per 256-thr block
  int c = threadIdx.x & 127;                       // col chunk (8 elems)
  int e = 0, base = 0, acc = 0;
#pragma unroll
  for (int ee = 0; ee < NEXP; ee++) {
    int ce = cnt[ee];
    if (s >= acc && s < acc + ce) { e = ee; base = acc; }
    acc += ce;
  }
  int src = rowlist[(size_t)e*NROWS + (s - base)];
  const float* sp = x + (size_t)src*KDIM + c*8;
  float4 v0 = *(const float4*)(sp);
  float4 v1 = *(const float4*)(sp + 4);
  bf16x8 o = { (bf16_t)v0.x, (bf16_t)v0.y, (bf16_t)v0.z, (bf16_t)v0.w,
               (bf16_t)v1.x, (bf16_t)v1.y, (bf16_t)v1.z, (bf16_t)v1.w };
  *(bf16x8*)(xp + (size_t)s*KDIM + c*8) = o;
  if (c == 0) inv[src] = s;
}

// ---------------- 3. convert+transpose w -> bf16 [E][N][K] ----------------
__global__ void cvt_w_kernel(const float* __restrict__ w, bf16_t* __restrict__ wb) {
  __shared__ float tf[64*65];
  int e  = blockIdx.z;
  int n0 = blockIdx.x * 64;
  int k0 = blockIdx.y * 64;
  int t  = threadIdx.x;
  const float* src = w + (size_t)e*KDIM*NDIM + (size_t)k0*NDIM + n0;
#pragma unroll
  for (int i = 0; i < 4; i++) {
    int idx = t + i*256;
    int kr  = idx >> 4;
    int nc4 = (idx & 15) * 4;
    float4 v = *(const float4*)(src + (size_t)kr*NDIM + nc4);
    tf[kr*65 + nc4+0] = v.x; tf[kr*65 + nc4+1] = v.y;
    tf[kr*65 + nc4+2] = v.z; tf[kr*65 + nc4+3] = v.w;
  }
  __syncthreads();
  bf16_t* dst = wb + (size_t)e*NDIM*KDIM + (size_t)n0*KDIM + k0;
#pragma unroll
  for (int i = 0; i < 2; i++) {
    int idx = t + i*256;
    int nr  = idx >> 3;
    int kc  = (idx & 7) * 8;
    bf16x8 o;
#pragma unroll
    for (int j = 0; j < 8; j++) o[j] = (bf16_t)tf[(kc+j)*65 + nr];
    *(bf16x8*)(dst + (size_t)nr*KDIM + kc) = o;
  }
}

// ---------------- 4. dense per-expert GEMM: 128x256, BK=64, DOUBLE-buffered --
// 8 waves (2M x 4N), per-wave 64x64. 1-barrier-per-phase schedule (T3 2-phase):
//   barrier; STAGE(buf^1, tile+1); COMPUTE(buf, tile); barrier; ...
// DMA drain for STAGE lands at the barrier AFTER the overlapped COMPUTE ->
// latency hidden under 24 ds_reads + 32 MFMAs. LDS 96KB = 2 x (A 16KB + B 32KB).
// Swizzle (r8-proven, 0 conflicts): phys 16B slot = logical ^ (row&7).
#define ABASE(B) ((B)*49152)
#define BBASE(B) ((B)*49152 + 16384)

#define STAGE(B) do {                                                          \
    gload_lds16(gA0, smem + ABASE(B) + t*16);                                  \
    gload_lds16(gA1, smem + ABASE(B) + t*16 + 8192);                           \
    gload_lds16(gBb,            smem + BBASE(B) + t*16);                       \
    gload_lds16(gBb + 64*KDIM,  smem + BBASE(B) + t*16 + 8192);                \
    gload_lds16(gBb + 128*KDIM, smem + BBASE(B) + t*16 + 16384);               \
    gload_lds16(gBb + 192*KDIM, smem + BBASE(B) + t*16 + 24576);               \
    gA0 += BK; gA1 += BK; gBb += BK;                                           \
  } while (0)

#define COMPUTE(B) do {                                                        \
    bf16x8 af[4][2], bfv[4][2];                                                \
    _Pragma("unroll") for (int mi = 0; mi < 4; mi++) {                         \
      af[mi][0] = *(const bf16x8*)&smem[ABASE(B) + aoff0 + mi*2048];           \
      af[mi][1] = *(const bf16x8*)&smem[(ABASE(B) + aoff0 + mi*2048) ^ 64];    \
    }                                                                          \
    _Pragma("unroll") for (int ni = 0; ni < 4; ni++) {                         \
      bfv[ni][0] = *(const bf16x8*)&smem[BBASE(B) + boff0 + ni*2048];          \
      bfv[ni][1] = *(const bf16x8*)&smem[(BBASE(B) + boff0 + ni*2048) ^ 64];   \
    }                                                                          \
    _Pragma("unroll") for (int mi = 0; mi < 4; mi++)                           \
      _Pragma("unroll") for (int ni = 0; ni < 4; ni++) {                       \
        acc[mi][ni] = __builtin_amdgcn_mfma_f32_16x16x32_bf16(af[mi][0], bfv[ni][0], acc[mi][ni], 0, 0, 0); \
        acc[mi][ni] = __builtin_amdgcn_mfma_f32_16x16x32_bf16(af[mi][1], bfv[ni][1], acc[mi][ni], 0, 0, 0); \
      }                                                                        \
  } while (0)

__global__ __launch_bounds__(512)
void gemm_kernel(const bf16_t* __restrict__ xp,     // [NROWS][KDIM] permuted
                 const bf16_t* __restrict__ wb,     // [NEXP][NDIM][KDIM]
                 const int*    __restrict__ cnt,
                 bf16_t*       __restrict__ scrb) { // [NROWS][NDIM] permuted
  extern __shared__ char smem[];   // 98304 B

  // XCD-bijective swizzle: 1088 = 8*136, n-tile fastest
  int bid = blockIdx.x;
  int lin = (bid & 7) * (GRID_G/8) + (bid >> 3);
  int xt  = lin & (NXT-1);
  int yt  = lin >> 3;

  // inline worklist: expert + row range for this 128-row tile
  int e = -1, rowbase = 0, nrows = 0;
  {
    int a0 = 0, rb = 0;
#pragma unroll
    for (int ee = 0; ee < NEXP; ee++) {
      int c  = cnt[ee];
      int nt = (c + TM - 1) >> 7;
      if (yt >= a0 && yt < a0 + nt) {
        e = ee; rowbase = rb + (yt - a0)*TM;
        nrows = c - (yt - a0)*TM; if (nrows > TM) nrows = TM;
      }
      a0 += nt; rb += c;
    }
  }
  if (e < 0) return;
  const int n0 = xt * TN;

  const int t    = threadIdx.x;
  const int lane = t & 63;
  const int wv   = t >> 6;         // 0..7
  const int wm   = wv >> 2;        // 0..1
  const int wn   = wv & 3;         // 0..3
  const int lr   = lane & 15;
  const int l4   = lane >> 4;

  // ---- staging: thread t -> row t>>3 (+64i), phys slot t&7, dest linear t*16
  const int koff = ((t & 7) ^ ((t >> 3) & 7)) * 8;
  int ar0 = rowbase + (t >> 3);       if (ar0 > NROWS-1) ar0 = NROWS-1;
  int ar1 = rowbase + (t >> 3) + 64;  if (ar1 > NROWS-1) ar1 = NROWS-1;
  const bf16_t* gA0 = xp + (size_t)ar0*KDIM + koff;
  const bf16_t* gA1 = xp + (size_t)ar1*KDIM + koff;
  const bf16_t* gBb = wb + ((size_t)e*NDIM + n0 + (t >> 3))*KDIM + koff;

  // ---- fragment read offsets (byte, swizzled) ----
  const int aoff0 = (wm*64 + lr)*128 + ((l4 ^ (lr & 7)) << 4);
  const int boff0 = (wn*64 + lr)*128 + ((l4 ^ (lr & 7)) << 4);

  f32x4 acc[4][4] = {};

  // ---- prologue: stage tile 0 into buf0 ----
  STAGE(0);

  // ---- main loop: 8 iterations x 2 K-tiles ----
#pragma unroll 1
  for (int it = 0; it < 8; ++it) {
    __syncthreads();                 // buf0 staged; prior reads of buf1 done
    STAGE(1);                        // tile 2it+1; flies under COMPUTE(0)
    COMPUTE(0);                      // tile 2it
    __syncthreads();                 // buf1 staged; reads of buf0 done
    if (it != 7) STAGE(0);           // tile 2it+2; flies under COMPUTE(1)
    COMPUTE(1);                      // tile 2it+1
  }

  // ---- epilogue: sequential slot rows ----
#pragma unroll
  for (int mi = 0; mi < 4; mi++) {
#pragma unroll
    for (int jj = 0; jj < 4; jj++) {
      int rbw = wm*64 + mi*16 + l4*4 + jj;
      if (rbw < nrows) {
        bf16_t* dst = scrb + (size_t)(rowbase + rbw)*NDIM + n0 + wn*64 + lr;
#pragma unroll
        for (int ni = 0; ni < 4; ni++) dst[ni*16] = (bf16_t)acc[mi][ni][jj];
      }
    }
  }
}

// ---------------- 5. reduce: out[t] = tw0*scr[inv[2t]] + tw1*scr[inv[2t+1]] --
__global__ void reduce_kernel(const bf16_t* __restrict__ scr,
                              const int* __restrict__ inv,
                              const float* __restrict__ tw,
                              float* __restrict__ out) {
  int tk = blockIdx.x;                 // token
  int c  = threadIdx.x;                // 256 threads, 8 cols each
  int2  iv = *(const int2*)(inv + 2*tk);
  float w0 = tw[2*tk], w1 = tw[2*tk+1];
  bf16x8 a = *(const bf16x8*)(scr + (size_t)iv.x*NDIM + c*8);
  bf16x8 b = *(const bf16x8*)(scr + (size_t)iv.y*NDIM + c*8);
  float4 o0 = { w0*(float)a[0]+w1*(float)b[0], w0*(float)a[1]+w1*(float)b[1],
                w0*(float)a[2]+w1*(float)b[2], w0*(float)a[3]+w1*(float)b[3] };
  float4 o1 = { w0*(float)a[4]+w1*(float)b[4], w0*(float)a[5]+w1*(float)b[5],
                w0*(float)a[6]+w1*(float)b[6], w0*(float)a[7]+w1*(float)b[7] };
  float* dst = out + (size_t)tk*NDIM + c*8;
  *(float4*)(dst)     = o0;
  *(float4*)(dst + 4) = o1;
}

// ---------------- launch ----------------
extern "C" void kernel_launch(void* const* d_in, const int* in_sizes, int n_in,
                              void* d_out, int out_size, void* d_ws, size_t ws_size,
                              hipStream_t stream) {
  const float* x      = (const float*)d_in[0];
  const float* w      = (const float*)d_in[1];
  const float* logits = (const float*)d_in[2];
  float* out = (float*)d_out;

  char* ws = (char*)d_ws;
  float*  tw      = (float*)(ws + OFF_TW);
  int*    inv     = (int*)  (ws + OFF_INV);
  int*    cnt     = (int*)  (ws + OFF_CNT);
  int*    rowlist = (int*)  (ws + OFF_RL);
  bf16_t* xp      = (bf16_t*)(ws + OFF_XP);
  bf16_t* wb      = (bf16_t*)(ws + OFF_WB);
  bf16_t* scrb    = (bf16_t*)(ws + OFF_SCR);

  hipMemsetAsync(cnt, 0, NEXP * sizeof(int), stream);
  routing_kernel<<<NTOK/256, 256, 0, stream>>>(logits, tw, cnt, rowlist);
  cvt_x_perm_kernel<<<NROWS/2, 256, 0, stream>>>(x, cnt, rowlist, xp, inv);
  cvt_w_kernel<<<dim3(NDIM/64, KDIM/64, NEXP), 256, 0, stream>>>(w, wb);
  gemm_kernel<<<GRID_G, 512, 98304, stream>>>(xp, wb, cnt, scrb);
  reduce_kernel<<<NTOK, 256, 0, stream>>>(scrb, inv, tw, out);
}

// Round 11
// 222.457 us; speedup vs baseline: 1.1180x; 1.0138x over previous
//
#include <hip/hip_runtime.h>
#include <hip/hip_bf16.h>

// ---------------- problem constants ----------------
#define NTOK   8192
#define TOPK   2
#define NROWS  (NTOK*TOPK)      // 16384
#define NEXP   8
#define KDIM   1024             // inner (INTER)
#define NDIM   2048             // output (HIDDEN)
#define TM     128              // tile rows
#define TN     256              // tile cols
#define BK     32
#define MAXYT  136              // sum ceil(cnt_e/128) <= 128+8
#define NXT    (NDIM/TN)        // 8
#define GRID_G (MAXYT*NXT)      // 1088 = 8*136

typedef __bf16 bf16_t;
typedef __bf16 bf16x8 __attribute__((ext_vector_type(8)));
typedef float  f32x4  __attribute__((ext_vector_type(4)));

static_assert(sizeof(bf16x8) == 16, "bf16x8 must be 16B");

// ---------------- ws layout (bytes) ----------------
#define OFF_TW    ((size_t)0)                    // 16384 f32
#define OFF_INV   ((size_t)(1<<16))              // 16384 i32
#define OFF_CNT   ((size_t)(1<<17))              // 8 i32
#define OFF_RL    ((size_t)(1<<18))              // 8*16384 i32
#define OFF_XP    ((size_t)(1<<20))              // 16384*1024 bf16 = 32MB (permuted)
#define OFF_WB    ((size_t)(34u<<20))            // 8*2048*1024 bf16 = 32MB
#define OFF_SCR   ((size_t)(68u<<20))            // 16384*2048 bf16 = 64MB (permuted order)

__device__ __forceinline__ void gload_lds16(const bf16_t* g, const char* l) {
  __builtin_amdgcn_global_load_lds(
      (const __attribute__((address_space(1))) void*)g,
      (__attribute__((address_space(3))) void*)(void*)l, 16, 0, 0);
}

// ---------------- 1. routing: softmax + top2 + bucket ----------------
__global__ void routing_kernel(const float* __restrict__ logits,
                               float* __restrict__ tw,
                               int* __restrict__ cnt, int* __restrict__ rowlist) {
  int t = blockIdx.x * blockDim.x + threadIdx.x;
  if (t >= NTOK) return;
  float4 a = *(const float4*)(logits + (size_t)t*NEXP);
  float4 b = *(const float4*)(logits + (size_t)t*NEXP + 4);
  float l[8] = {a.x, a.y, a.z, a.w, b.x, b.y, b.z, b.w};
  float m = l[0];
#pragma unroll
  for (int i = 1; i < 8; i++) m = fmaxf(m, l[i]);
  float p[8], s = 0.f;
#pragma unroll
  for (int i = 0; i < 8; i++) { p[i] = __expf(l[i] - m); s += p[i]; }
  int e0 = 0; float b0 = p[0];
#pragma unroll
  for (int i = 1; i < 8; i++) if (p[i] > b0) { b0 = p[i]; e0 = i; }
  int e1 = (e0 == 0) ? 1 : 0; float b1 = p[e1];
#pragma unroll
  for (int i = 0; i < 8; i++) if (i != e0 && p[i] > b1) { b1 = p[i]; e1 = i; }
  float inv = 1.f / s;
  tw[2*t]   = b0 * inv;
  tw[2*t+1] = b1 * inv;
  int pos0 = atomicAdd(&cnt[e0], 1);
  rowlist[(size_t)e0*NROWS + pos0] = 2*t;
  int pos1 = atomicAdd(&cnt[e1], 1);
  rowlist[(size_t)e1*NROWS + pos1] = 2*t + 1;
}

// ---------------- 2. cvt_x_perm: x -> bf16, expert-sorted order; emit inv ----
__global__ void cvt_x_perm_kernel(const float* __restrict__ x,
                                  const int* __restrict__ cnt,
                                  const int* __restrict__ rowlist,
                                  bf16_t* __restrict__ xp,
                                  int* __restrict__ inv) {
  int s = blockIdx.x * 2 + (threadIdx.x >> 7);     // 2 rows per 256-thr block
  int c = threadIdx.x & 127;                       // col chunk (8 elems)
  int e = 0, base = 0, acc = 0;
#pragma unroll
  for (int ee = 0; ee < NEXP; ee++) {
    int ce = cnt[ee];
    if (s >= acc && s < acc + ce) { e = ee; base = acc; }
    acc += ce;
  }
  int src = rowlist[(size_t)e*NROWS + (s - base)];
  const float* sp = x + (size_t)src*KDIM + c*8;
  float4 v0 = *(const float4*)(sp);
  float4 v1 = *(const float4*)(sp + 4);
  bf16x8 o = { (bf16_t)v0.x, (bf16_t)v0.y, (bf16_t)v0.z, (bf16_t)v0.w,
               (bf16_t)v1.x, (bf16_t)v1.y, (bf16_t)v1.z, (bf16_t)v1.w };
  *(bf16x8*)(xp + (size_t)s*KDIM + c*8) = o;
  if (c == 0) inv[src] = s;
}

// ---------------- 3. convert+transpose w -> bf16 [E][N][K] ----------------
__global__ void cvt_w_kernel(const float* __restrict__ w, bf16_t* __restrict__ wb) {
  __shared__ float tf[64*65];
  int e  = blockIdx.z;
  int n0 = blockIdx.x * 64;
  int k0 = blockIdx.y * 64;
  int t  = threadIdx.x;
  const float* src = w + (size_t)e*KDIM*NDIM + (size_t)k0*NDIM + n0;
#pragma unroll
  for (int i = 0; i < 4; i++) {
    int idx = t + i*256;
    int kr  = idx >> 4;
    int nc4 = (idx & 15) * 4;
    float4 v = *(const float4*)(src + (size_t)kr*NDIM + nc4);
    tf[kr*65 + nc4+0] = v.x; tf[kr*65 + nc4+1] = v.y;
    tf[kr*65 + nc4+2] = v.z; tf[kr*65 + nc4+3] = v.w;
  }
  __syncthreads();
  bf16_t* dst = wb + (size_t)e*NDIM*KDIM + (size_t)n0*KDIM + k0;
#pragma unroll
  for (int i = 0; i < 2; i++) {
    int idx = t + i*256;
    int nr  = idx >> 3;
    int kc  = (idx & 7) * 8;
    bf16x8 o;
#pragma unroll
    for (int j = 0; j < 8; j++) o[j] = (bf16_t)tf[(kc+j)*65 + nr];
    *(bf16x8*)(dst + (size_t)nr*KDIM + kc) = o;
  }
}

// ---------------- 4. dense per-expert GEMM: 128x256, BK=32, dbuf-in-48KB -----
// 8 waves (2M x 4N), per-wave 64x64. Per iter: 1 barrier; STAGE(buf^1) issues
// 3 DMA units that fly across COMPUTE(buf) (16 MFMA + 8 ds_read) and drain at
// the NEXT barrier. 48KB total keeps 2 blocks/CU (r8 occupancy) — r10's dbuf
// at 96KB lost that. Swizzle = r2's zero-conflict involution:
// phys 16B slot = logical ^ ((row>>1)&3); rows are 64B.
#define ABUF(B) ((B)*24576)
#define BBUF(B) ((B)*24576 + 8192)

#define STAGE(B) do {                                                          \
    gload_lds16(gA,             smem + ABUF(B) + t*16);                        \
    gload_lds16(gB0,            smem + BBUF(B) + t*16);                        \
    gload_lds16(gB1,            smem + BBUF(B) + t*16 + 8192);                 \
    gA += BK; gB0 += BK; gB1 += BK;                                            \
  } while (0)

#define COMPUTE(B) do {                                                        \
    bf16x8 af[4], bfv[4];                                                      \
    _Pragma("unroll") for (int mi = 0; mi < 4; mi++)                           \
      af[mi] = *(const bf16x8*)&smem[ABUF(B) + aoff0 + mi*1024];               \
    _Pragma("unroll") for (int ni = 0; ni < 4; ni++)                           \
      bfv[ni] = *(const bf16x8*)&smem[BBUF(B) + boff0 + ni*1024];              \
    _Pragma("unroll") for (int mi = 0; mi < 4; mi++)                           \
      _Pragma("unroll") for (int ni = 0; ni < 4; ni++)                         \
        acc[mi][ni] = __builtin_amdgcn_mfma_f32_16x16x32_bf16(                 \
            af[mi], bfv[ni], acc[mi][ni], 0, 0, 0);                            \
  } while (0)

__global__ __launch_bounds__(512)
void gemm_kernel(const bf16_t* __restrict__ xp,     // [NROWS][KDIM] permuted
                 const bf16_t* __restrict__ wb,     // [NEXP][NDIM][KDIM]
                 const int*    __restrict__ cnt,
                 bf16_t*       __restrict__ scrb) { // [NROWS][NDIM] permuted
  __shared__ char smem[49152];

  // XCD-bijective swizzle: 1088 = 8*136, n-tile fastest
  int bid = blockIdx.x;
  int lin = (bid & 7) * (GRID_G/8) + (bid >> 3);
  int xt  = lin & (NXT-1);
  int yt  = lin >> 3;

  // inline worklist: expert + row range for this 128-row tile
  int e = -1, rowbase = 0, nrows = 0;
  {
    int a0 = 0, rb = 0;
#pragma unroll
    for (int ee = 0; ee < NEXP; ee++) {
      int c  = cnt[ee];
      int nt = (c + TM - 1) >> 7;
      if (yt >= a0 && yt < a0 + nt) {
        e = ee; rowbase = rb + (yt - a0)*TM;
        nrows = c - (yt - a0)*TM; if (nrows > TM) nrows = TM;
      }
      a0 += nt; rb += c;
    }
  }
  if (e < 0) return;
  const int n0 = xt * TN;

  const int t    = threadIdx.x;
  const int lane = t & 63;
  const int wv   = t >> 6;         // 0..7
  const int wm   = wv >> 2;        // 0..1
  const int wn   = wv & 3;         // 0..3
  const int lr   = lane & 15;
  const int l4   = lane >> 4;

  // ---- staging: thread t -> row t>>2, phys slot t&3, dest linear t*16 ----
  // source logical slot = (t&3) ^ ((t>>3)&3)  [r2-proven involution]
  const int koff = ((t & 3) ^ ((t >> 3) & 3)) * 8;
  int ar = rowbase + (t >> 2);  if (ar > NROWS-1) ar = NROWS-1;
  const bf16_t* gA  = xp + (size_t)ar*KDIM + koff;
  const bf16_t* gB0 = wb + ((size_t)e*NDIM + n0 + (t >> 2))*KDIM + koff;
  const bf16_t* gB1 = gB0 + (size_t)128*KDIM;

  // ---- fragment read offsets (byte): row 64B, phys = l4 ^ ((lr>>1)&3) ----
  const int aoff0 = (wm*64 + lr)*64 + ((l4 ^ ((lr >> 1) & 3)) << 4);
  const int boff0 = (wn*64 + lr)*64 + ((l4 ^ ((lr >> 1) & 3)) << 4);

  f32x4 acc[4][4] = {};

  // ---- prologue: stage tile 0 into buf0 ----
  STAGE(0);

  // ---- main loop: 16 outer iters x 2 K-steps (KDIM/BK = 32) ----
#pragma unroll 1
  for (int it = 0; it < 16; ++it) {
    __syncthreads();               // drains DMA staged last phase (flew across COMPUTE)
    STAGE(1);                      // tile 2it+1, flies across COMPUTE(0)
    COMPUTE(0);                    // tile 2it
    __syncthreads();
    if (it != 15) STAGE(0);        // tile 2it+2, flies across COMPUTE(1)
    COMPUTE(1);                    // tile 2it+1
  }

  // ---- epilogue: sequential slot rows ----
#pragma unroll
  for (int mi = 0; mi < 4; mi++) {
#pragma unroll
    for (int jj = 0; jj < 4; jj++) {
      int rbw = wm*64 + mi*16 + l4*4 + jj;
      if (rbw < nrows) {
        bf16_t* dst = scrb + (size_t)(rowbase + rbw)*NDIM + n0 + wn*64 + lr;
#pragma unroll
        for (int ni = 0; ni < 4; ni++) dst[ni*16] = (bf16_t)acc[mi][ni][jj];
      }
    }
  }
}

// ---------------- 5. reduce: out[t] = tw0*scr[inv[2t]] + tw1*scr[inv[2t+1]] --
__global__ void reduce_kernel(const bf16_t* __restrict__ scr,
                              const int* __restrict__ inv,
                              const float* __restrict__ tw,
                              float* __restrict__ out) {
  int tk = blockIdx.x;                 // token
  int c  = threadIdx.x;                // 256 threads, 8 cols each
  int2  iv = *(const int2*)(inv + 2*tk);
  float w0 = tw[2*tk], w1 = tw[2*tk+1];
  bf16x8 a = *(const bf16x8*)(scr + (size_t)iv.x*NDIM + c*8);
  bf16x8 b = *(const bf16x8*)(scr + (size_t)iv.y*NDIM + c*8);
  float4 o0 = { w0*(float)a[0]+w1*(float)b[0], w0*(float)a[1]+w1*(float)b[1],
                w0*(float)a[2]+w1*(float)b[2], w0*(float)a[3]+w1*(float)b[3] };
  float4 o1 = { w0*(float)a[4]+w1*(float)b[4], w0*(float)a[5]+w1*(float)b[5],
                w0*(float)a[6]+w1*(float)b[6], w0*(float)a[7]+w1*(float)b[7] };
  float* dst = out + (size_t)tk*NDIM + c*8;
  *(float4*)(dst)     = o0;
  *(float4*)(dst + 4) = o1;
}

// ---------------- launch ----------------
extern "C" void kernel_launch(void* const* d_in, const int* in_sizes, int n_in,
                              void* d_out, int out_size, void* d_ws, size_t ws_size,
                              hipStream_t stream) {
  const float* x      = (const float*)d_in[0];
  const float* w      = (const float*)d_in[1];
  const float* logits = (const float*)d_in[2];
  float* out = (float*)d_out;

  char* ws = (char*)d_ws;
  float*  tw      = (float*)(ws + OFF_TW);
  int*    inv     = (int*)  (ws + OFF_INV);
  int*    cnt     = (int*)  (ws + OFF_CNT);
  int*    rowlist = (int*)  (ws + OFF_RL);
  bf16_t* xp      = (bf16_t*)(ws + OFF_XP);
  bf16_t* wb      = (bf16_t*)(ws + OFF_WB);
  bf16_t* scrb    = (bf16_t*)(ws + OFF_SCR);

  hipMemsetAsync(cnt, 0, NEXP * sizeof(int), stream);
  routing_kernel<<<NTOK/256, 256, 0, stream>>>(logits, tw, cnt, rowlist);
  cvt_x_perm_kernel<<<NROWS/2, 256, 0, stream>>>(x, cnt, rowlist, xp, inv);
  cvt_w_kernel<<<dim3(NDIM/64, KDIM/64, NEXP), 256, 0, stream>>>(w, wb);
  gemm_kernel<<<GRID_G, 512, 0, stream>>>(xp, wb, cnt, scrb);
  reduce_kernel<<<NTOK, 256, 0, stream>>>(scrb, inv, tw, out);
}

// Round 12
// 207.546 us; speedup vs baseline: 1.1983x; 1.0718x over previous
//
#include <hip/hip_runtime.h>
#include <hip/hip_bf16.h>

// ---------------- problem constants ----------------
#define NTOK   8192
#define TOPK   2
#define NROWS  (NTOK*TOPK)      // 16384
#define NEXP   8
#define KDIM   1024             // inner (INTER)
#define NDIM   2048             // output (HIDDEN)
#define TM     128              // tile rows
#define TN     256              // tile cols
#define BK     64
#define MAXYT  136              // sum ceil(cnt_e/128) <= 128+8
#define NXT    (NDIM/TN)        // 8
#define GRID_G (MAXYT*NXT)      // 1088 = 8*136

typedef __bf16 bf16_t;
typedef __bf16 bf16x8 __attribute__((ext_vector_type(8)));
typedef float  f32x4  __attribute__((ext_vector_type(4)));

static_assert(sizeof(bf16x8) == 16, "bf16x8 must be 16B");

// ---------------- ws layout (bytes) ----------------
#define OFF_TW    ((size_t)0)                    // 16384 f32
#define OFF_INV   ((size_t)(1<<16))              // 16384 i32
#define OFF_CNT   ((size_t)(1<<17))              // 8 i32
#define OFF_RL    ((size_t)(1<<18))              // 8*16384 i32
#define OFF_XP    ((size_t)(1<<20))              // 16384*1024 bf16 = 32MB (permuted)
#define OFF_WB    ((size_t)(34u<<20))            // 8*2048*1024 bf16 = 32MB
#define OFF_SCR   ((size_t)(68u<<20))            // 16384*2048 bf16 = 64MB (permuted order)

__device__ __forceinline__ void gload_lds16(const bf16_t* g, const char* l) {
  __builtin_amdgcn_global_load_lds(
      (const __attribute__((address_space(1))) void*)g,
      (__attribute__((address_space(3))) void*)(void*)l, 16, 0, 0);
}

// ---------------- 1. fused prep: routing (blocks 0..31) + cvt_w (32..4127) ---
// routing: softmax + top2 + atomic bucket.  cvt_w: fp32 w -> bf16 [E][N][K]
// (independent of routing -> safe to fuse by block range).
__global__ void prep_kernel(const float* __restrict__ logits,
                            float* __restrict__ tw,
                            int* __restrict__ cnt, int* __restrict__ rowlist,
                            const float* __restrict__ w, bf16_t* __restrict__ wb) {
  __shared__ float tf[64*65];
  int bid = blockIdx.x;
  int tid = threadIdx.x;

  if (bid < 32) {
    // ---------- routing ----------
    int t = bid * 256 + tid;
    float4 a = *(const float4*)(logits + (size_t)t*NEXP);
    float4 b = *(const float4*)(logits + (size_t)t*NEXP + 4);
    float l[8] = {a.x, a.y, a.z, a.w, b.x, b.y, b.z, b.w};
    float m = l[0];
#pragma unroll
    for (int i = 1; i < 8; i++) m = fmaxf(m, l[i]);
    float p[8], s = 0.f;
#pragma unroll
    for (int i = 0; i < 8; i++) { p[i] = __expf(l[i] - m); s += p[i]; }
    int e0 = 0; float b0 = p[0];
#pragma unroll
    for (int i = 1; i < 8; i++) if (p[i] > b0) { b0 = p[i]; e0 = i; }
    int e1 = (e0 == 0) ? 1 : 0; float b1 = p[e1];
#pragma unroll
    for (int i = 0; i < 8; i++) if (i != e0 && p[i] > b1) { b1 = p[i]; e1 = i; }
    float inv = 1.f / s;
    tw[2*t]   = b0 * inv;
    tw[2*t+1] = b1 * inv;
    int pos0 = atomicAdd(&cnt[e0], 1);
    rowlist[(size_t)e0*NROWS + pos0] = 2*t;
    int pos1 = atomicAdd(&cnt[e1], 1);
    rowlist[(size_t)e1*NROWS + pos1] = 2*t + 1;
    return;
  }

  // ---------- cvt_w: 64n x 64k tile ----------
  int id = bid - 32;                 // 0..4095
  int e  = id >> 9;                  // 0..7
  int k0 = ((id >> 5) & 15) * 64;    // 0..960
  int n0 = (id & 31) * 64;           // 0..1984
  const float* src = w + (size_t)e*KDIM*NDIM + (size_t)k0*NDIM + n0;
#pragma unroll
  for (int i = 0; i < 4; i++) {
    int idx = tid + i*256;
    int kr  = idx >> 4;
    int nc4 = (idx & 15) * 4;
    float4 v = *(const float4*)(src + (size_t)kr*NDIM + nc4);
    tf[kr*65 + nc4+0] = v.x; tf[kr*65 + nc4+1] = v.y;
    tf[kr*65 + nc4+2] = v.z; tf[kr*65 + nc4+3] = v.w;
  }
  __syncthreads();
  bf16_t* dst = wb + (size_t)e*NDIM*KDIM + (size_t)n0*KDIM + k0;
#pragma unroll
  for (int i = 0; i < 2; i++) {
    int idx = tid + i*256;
    int nr  = idx >> 3;
    int kc  = (idx & 7) * 8;
    bf16x8 o;
#pragma unroll
    for (int j = 0; j < 8; j++) o[j] = (bf16_t)tf[(kc+j)*65 + nr];
    *(bf16x8*)(dst + (size_t)nr*KDIM + kc) = o;
  }
}

// ---------------- 2. cvt_x_perm: x -> bf16, expert-sorted order; emit inv ----
__global__ void cvt_x_perm_kernel(const float* __restrict__ x,
                                  const int* __restrict__ cnt,
                                  const int* __restrict__ rowlist,
                                  bf16_t* __restrict__ xp,
                                  int* __restrict__ inv) {
  int s = blockIdx.x * 4 + (threadIdx.x >> 7);     // 4 rows per 512-thr block
  int c = threadIdx.x & 127;                       // col chunk (8 elems)
  int e = 0, base = 0, acc = 0;
#pragma unroll
  for (int ee = 0; ee < NEXP; ee++) {
    int ce = cnt[ee];
    if (s >= acc && s < acc + ce) { e = ee; base = acc; }
    acc += ce;
  }
  int src = rowlist[(size_t)e*NROWS + (s - base)];
  const float* sp = x + (size_t)src*KDIM + c*8;
  float4 v0 = *(const float4*)(sp);
  float4 v1 = *(const float4*)(sp + 4);
  bf16x8 o = { (bf16_t)v0.x, (bf16_t)v0.y, (bf16_t)v0.z, (bf16_t)v0.w,
               (bf16_t)v1.x, (bf16_t)v1.y, (bf16_t)v1.z, (bf16_t)v1.w };
  *(bf16x8*)(xp + (size_t)s*KDIM + c*8) = o;
  if (c == 0) inv[src] = s;
}

// ---------------- 3. dense per-expert GEMM: 128x256, BK=64 (r8-proven) ------
// 8 waves (2M x 4N), per-wave 64x64, 32 MFMA per barrier-pair. LDS 48KB:
// A[128][64] @0, B[256][64] @16384; phys 16B slot = logical ^ (row&7);
// DMA dest linear (t*16).
__global__ __launch_bounds__(512)
void gemm_kernel(const bf16_t* __restrict__ xp,     // [NROWS][KDIM] permuted
                 const bf16_t* __restrict__ wb,     // [NEXP][NDIM][KDIM]
                 const int*    __restrict__ cnt,
                 bf16_t*       __restrict__ scrb) { // [NROWS][NDIM] permuted
  __shared__ char smem[49152];

  // XCD-bijective swizzle: 1088 = 8*136, n-tile fastest
  int bid = blockIdx.x;
  int lin = (bid & 7) * (GRID_G/8) + (bid >> 3);
  int xt  = lin & (NXT-1);
  int yt  = lin >> 3;

  // inline worklist: expert + row range for this 128-row tile
  int e = -1, rowbase = 0, nrows = 0;
  {
    int a0 = 0, rb = 0;
#pragma unroll
    for (int ee = 0; ee < NEXP; ee++) {
      int c  = cnt[ee];
      int nt = (c + TM - 1) >> 7;
      if (yt >= a0 && yt < a0 + nt) {
        e = ee; rowbase = rb + (yt - a0)*TM;
        nrows = c - (yt - a0)*TM; if (nrows > TM) nrows = TM;
      }
      a0 += nt; rb += c;
    }
  }
  if (e < 0) return;
  const int n0 = xt * TN;

  const int t    = threadIdx.x;
  const int lane = t & 63;
  const int wv   = t >> 6;         // 0..7
  const int wm   = wv >> 2;        // 0..1
  const int wn   = wv & 3;         // 0..3
  const int lr   = lane & 15;
  const int l4   = lane >> 4;

  // ---- staging: thread t -> row t>>3 (+64i), phys slot t&7, dest linear ----
  const int koff = ((t & 7) ^ ((t >> 3) & 7)) * 8;
  int ar0 = rowbase + (t >> 3);       if (ar0 > NROWS-1) ar0 = NROWS-1;
  int ar1 = rowbase + (t >> 3) + 64;  if (ar1 > NROWS-1) ar1 = NROWS-1;
  const bf16_t* gA0 = xp + (size_t)ar0*KDIM + koff;
  const bf16_t* gA1 = xp + (size_t)ar1*KDIM + koff;
  const bf16_t* gBb = wb + ((size_t)e*NDIM + n0 + (t >> 3))*KDIM + koff;
  const char* dA = &smem[t*16];
  const char* dB = &smem[16384 + t*16];

  // ---- fragment read offsets (byte, swizzled) ----
  const int aoff0 = (wm*64 + lr)*128 + ((l4 ^ (lr & 7)) << 4);
  const int boff0 = 16384 + (wn*64 + lr)*128 + ((l4 ^ (lr & 7)) << 4);

  f32x4 acc[4][4] = {};

#pragma unroll 1
  for (int kt = 0; kt < KDIM/BK; ++kt) {
    __syncthreads();                 // previous reads done
    gload_lds16(gA0, dA);
    gload_lds16(gA1, dA + 8192);
    gload_lds16(gBb,            dB);
    gload_lds16(gBb + 64*KDIM,  dB + 8192);
    gload_lds16(gBb + 128*KDIM, dB + 16384);
    gload_lds16(gBb + 192*KDIM, dB + 24576);
    gA0 += BK; gA1 += BK; gBb += BK;
    __syncthreads();                 // staged data visible

    bf16x8 af[4][2], bf[4][2];
#pragma unroll
    for (int mi = 0; mi < 4; mi++) {
      af[mi][0] = *(const bf16x8*)&smem[aoff0 + mi*2048];
      af[mi][1] = *(const bf16x8*)&smem[(aoff0 + mi*2048) ^ 64];
    }
#pragma unroll
    for (int ni = 0; ni < 4; ni++) {
      bf[ni][0] = *(const bf16x8*)&smem[boff0 + ni*2048];
      bf[ni][1] = *(const bf16x8*)&smem[(boff0 + ni*2048) ^ 64];
    }
#pragma unroll
    for (int mi = 0; mi < 4; mi++)
#pragma unroll
      for (int ni = 0; ni < 4; ni++) {
        acc[mi][ni] = __builtin_amdgcn_mfma_f32_16x16x32_bf16(af[mi][0], bf[ni][0], acc[mi][ni], 0, 0, 0);
        acc[mi][ni] = __builtin_amdgcn_mfma_f32_16x16x32_bf16(af[mi][1], bf[ni][1], acc[mi][ni], 0, 0, 0);
      }
  }

  // ---- epilogue: sequential slot rows ----
#pragma unroll
  for (int mi = 0; mi < 4; mi++) {
#pragma unroll
    for (int jj = 0; jj < 4; jj++) {
      int rbw = wm*64 + mi*16 + l4*4 + jj;
      if (rbw < nrows) {
        bf16_t* dst = scrb + (size_t)(rowbase + rbw)*NDIM + n0 + wn*64 + lr;
#pragma unroll
        for (int ni = 0; ni < 4; ni++) dst[ni*16] = (bf16_t)acc[mi][ni][jj];
      }
    }
  }
}

// ---------------- 4. reduce: out[t] = tw0*scr[inv[2t]] + tw1*scr[inv[2t+1]] --
// 512 threads, 2 tokens per block.
__global__ void reduce_kernel(const bf16_t* __restrict__ scr,
                              const int* __restrict__ inv,
                              const float* __restrict__ tw,
                              float* __restrict__ out) {
  int tk = blockIdx.x * 2 + (threadIdx.x >> 8);
  int c  = threadIdx.x & 255;          // 8 cols each
  int2  iv = *(const int2*)(inv + 2*tk);
  float w0 = tw[2*tk], w1 = tw[2*tk+1];
  bf16x8 a = *(const bf16x8*)(scr + (size_t)iv.x*NDIM + c*8);
  bf16x8 b = *(const bf16x8*)(scr + (size_t)iv.y*NDIM + c*8);
  float4 o0 = { w0*(float)a[0]+w1*(float)b[0], w0*(float)a[1]+w1*(float)b[1],
                w0*(float)a[2]+w1*(float)b[2], w0*(float)a[3]+w1*(float)b[3] };
  float4 o1 = { w0*(float)a[4]+w1*(float)b[4], w0*(float)a[5]+w1*(float)b[5],
                w0*(float)a[6]+w1*(float)b[6], w0*(float)a[7]+w1*(float)b[7] };
  float* dst = out + (size_t)tk*NDIM + c*8;
  *(float4*)(dst)     = o0;
  *(float4*)(dst + 4) = o1;
}

// ---------------- launch ----------------
extern "C" void kernel_launch(void* const* d_in, const int* in_sizes, int n_in,
                              void* d_out, int out_size, void* d_ws, size_t ws_size,
                              hipStream_t stream) {
  const float* x      = (const float*)d_in[0];
  const float* w      = (const float*)d_in[1];
  const float* logits = (const float*)d_in[2];
  float* out = (float*)d_out;

  char* ws = (char*)d_ws;
  float*  tw      = (float*)(ws + OFF_TW);
  int*    inv     = (int*)  (ws + OFF_INV);
  int*    cnt     = (int*)  (ws + OFF_CNT);
  int*    rowlist = (int*)  (ws + OFF_RL);
  bf16_t* xp      = (bf16_t*)(ws + OFF_XP);
  bf16_t* wb      = (bf16_t*)(ws + OFF_WB);
  bf16_t* scrb    = (bf16_t*)(ws + OFF_SCR);

  hipMemsetAsync(cnt, 0, NEXP * sizeof(int), stream);
  prep_kernel<<<32 + 4096, 256, 0, stream>>>(logits, tw, cnt, rowlist, w, wb);
  cvt_x_perm_kernel<<<NROWS/4, 512, 0, stream>>>(x, cnt, rowlist, xp, inv);
  gemm_kernel<<<GRID_G, 512, 0, stream>>>(xp, wb, cnt, scrb);
  reduce_kernel<<<NTOK/2, 512, 0, stream>>>(scrb, inv, tw, out);
}